// Round 15
// baseline (309.145 us; speedup 1.0000x reference)
//
#include <hip/hip_runtime.h>
#include <math.h>

#define HC 128
#define NSLOPE 0.2f

using bf16x8 = __attribute__((ext_vector_type(8))) short;
using f32x4  = __attribute__((ext_vector_type(4))) float;

__device__ __forceinline__ float lrelu(float v){ return v > 0.f ? v : NSLOPE * v; }

// bf16 round-to-nearest-even pack / unpack
__device__ __forceinline__ unsigned short f2bf(float f){
    unsigned int b = __float_as_uint(f);
    b += 0x7FFFu + ((b >> 16) & 1u);
    return (unsigned short)(b >> 16);
}
__device__ __forceinline__ float bf_lo(unsigned int v){ return __uint_as_float(v << 16); }
__device__ __forceinline__ float bf_hi(unsigned int v){ return __uint_as_float(v & 0xFFFF0000u); }
__device__ __forceinline__ float bf1(unsigned short v){ return __uint_as_float((unsigned int)v << 16); }

// ----------------- CSR build (dst-sorted) -----------------
__global__ void count_kernel(const int* __restrict__ ei, int* __restrict__ cnt,
                             int* __restrict__ rank, int E){
    int e = blockIdx.x * blockDim.x + threadIdx.x;
    if (e < E) rank[e] = atomicAdd(&cnt[ei[E + e]], 1);
}

__global__ __launch_bounds__(256) void scan_part_kernel(
        const int* __restrict__ deg, int* __restrict__ bsum, int n)
{
    int t = threadIdx.x, lane = t & 63, wid = t >> 6;
    int base = blockIdx.x * 1024 + t * 4;
    int s = 0;
    #pragma unroll
    for (int j = 0; j < 4; ++j){ int i = base + j; if (i < n) s += deg[i]; }
    #pragma unroll
    for (int o = 1; o < 64; o <<= 1) s += __shfl_xor(s, o);
    __shared__ int red[4];
    if (lane == 0) red[wid] = s;
    __syncthreads();
    if (t == 0) bsum[blockIdx.x] = red[0] + red[1] + red[2] + red[3];
}

__global__ __launch_bounds__(64) void scan_top_kernel(
        const int* __restrict__ bsum, int* __restrict__ boff, int* __restrict__ rowptr,
        int nb, int n)
{
    int t = threadIdx.x;
    int v = (t < nb) ? bsum[t] : 0;
    int incl = v;
    #pragma unroll
    for (int o = 1; o < 64; o <<= 1){ int u = __shfl_up(incl, o); if (t >= o) incl += u; }
    if (t < nb) boff[t] = incl - v;
    if (t == 63) rowptr[n] = incl;
}

__global__ __launch_bounds__(256) void scan_fin_kernel(
        const int* __restrict__ deg, const int* __restrict__ boff,
        int* __restrict__ rowptr, int n)
{
    int t = threadIdx.x, lane = t & 63, wid = t >> 6;
    int base = blockIdx.x * 1024 + t * 4;
    int d[4]; int s = 0;
    #pragma unroll
    for (int j = 0; j < 4; ++j){ int i = base + j; d[j] = (i < n) ? deg[i] : 0; s += d[j]; }
    int incl = s;
    #pragma unroll
    for (int o = 1; o < 64; o <<= 1){ int u = __shfl_up(incl, o); if (lane >= o) incl += u; }
    __shared__ int wsum[4];
    if (lane == 63) wsum[wid] = incl;
    __syncthreads();
    int off = boff[blockIdx.x] + (incl - s);
    for (int w = 0; w < wid; ++w) off += wsum[w];
    #pragma unroll
    for (int j = 0; j < 4; ++j){
        int i = base + j;
        if (i < n) rowptr[i] = off;
        off += d[j];
    }
}

// stateless scatter, ILP=8
__global__ __launch_bounds__(256) void scatter_kernel(
        const int* __restrict__ ei, const int* __restrict__ rowptr,
        const int* __restrict__ rank, int* __restrict__ colsrc, int E)
{
    int b = blockIdx.x * 2048 + threadIdx.x;
    int e[8]; bool v[8]; int d[8], s[8], r[8];
    #pragma unroll
    for (int i = 0; i < 8; ++i){ e[i] = b + i * 256; v[i] = e[i] < E; }
    #pragma unroll
    for (int i = 0; i < 8; ++i) if (v[i]){ d[i] = ei[E + e[i]]; s[i] = ei[e[i]]; r[i] = rank[e[i]]; }
    #pragma unroll
    for (int i = 0; i < 8; ++i) if (v[i]) colsrc[rowptr[d[i]] + r[i]] = s[i];
}

// ----------------- all weight transposes -> bf16 Wt[c][K=128], one dispatch -----------------
__global__ __launch_bounds__(256) void wtrans_all_kernel(
        const float* __restrict__ w_n2, const float* __restrict__ conv_w,
        const float* __restrict__ wv1,
        unsigned short* __restrict__ Wt0, unsigned short* __restrict__ Wt1,
        unsigned short* __restrict__ Wtv)
{
    int idx = blockIdx.x * 256 + threadIdx.x;
    if (idx >= 9216) return;
    const float* Wm; unsigned short* Wo; int C; int rem;
    if (idx < 2048){ Wm = w_n2; Wo = Wt0; C = 128; rem = idx; }
    else if (idx < 8192){
        int m2 = (idx - 2048) >> 11; rem = (idx - 2048) & 2047;
        Wm = conv_w + (size_t)m2 * 16384; Wo = Wt1 + (size_t)m2 * 16384; C = 128;
    } else { rem = idx - 8192; Wm = wv1; Wo = Wtv; C = 64; }
    int c = rem >> 4, kg = rem & 15;
    unsigned int pk[4];
    #pragma unroll
    for (int j = 0; j < 4; ++j){
        float a = Wm[(size_t)(kg*8 + j*2    ) * C + c];
        float b = Wm[(size_t)(kg*8 + j*2 + 1) * C + c];
        pk[j] = (unsigned int)f2bf(a) | ((unsigned int)f2bf(b) << 16);
    }
    *(uint4*)(Wo + (size_t)c * 128 + kg * 8) = make_uint4(pk[0], pk[1], pk[2], pk[3]);
}

// ----------------- node encoder stage 1: hid(bf16) = relu(x@w1+b1), K=32 -----------------
__global__ __launch_bounds__(256) void enc1_kernel(
        const float* __restrict__ x, const float* __restrict__ w1, const float* __restrict__ b1,
        unsigned short* __restrict__ hid, int n)
{
    __shared__ float As[32][68];
    __shared__ float Bs[32][128];
    int t = threadIdx.x;
    int m0 = blockIdx.x * 64;
    int tm = t >> 4, tn = t & 15;

    #pragma unroll
    for (int i = 0; i < 2; ++i){
        int f = i * 256 + t;
        int row = f >> 3, kq = f & 7;
        int gr = m0 + row; if (gr > n - 1) gr = n - 1;
        float4 v = *(const float4*)(x + (size_t)gr * 32 + kq * 4);
        As[kq*4+0][row] = v.x; As[kq*4+1][row] = v.y; As[kq*4+2][row] = v.z; As[kq*4+3][row] = v.w;
    }
    #pragma unroll
    for (int i = 0; i < 4; ++i){
        int f = i * 256 + t;
        int kk = f >> 5, nq = f & 31;
        *(float4*)&Bs[kk][nq*4] = *(const float4*)(w1 + (size_t)kk * 128 + nq * 4);
    }
    __syncthreads();

    float acc[4][8];
    #pragma unroll
    for (int i = 0; i < 4; ++i)
        #pragma unroll
        for (int j = 0; j < 8; ++j) acc[i][j] = 0.f;

    #pragma unroll 4
    for (int k = 0; k < 32; ++k){
        float a[4], b[8];
        *(float4*)&a[0] = *(float4*)&As[k][tm*4];
        *(float4*)&b[0] = *(float4*)&Bs[k][tn*8];
        *(float4*)&b[4] = *(float4*)&Bs[k][tn*8+4];
        #pragma unroll
        for (int i = 0; i < 4; ++i)
            #pragma unroll
            for (int j = 0; j < 8; ++j) acc[i][j] = fmaf(a[i], b[j], acc[i][j]);
    }

    float bb[8];
    *(float4*)&bb[0] = *(const float4*)(b1 + tn*8);
    *(float4*)&bb[4] = *(const float4*)(b1 + tn*8 + 4);
    #pragma unroll
    for (int i = 0; i < 4; ++i){
        int node = m0 + tm*4 + i;
        if (node < n){
            float o[8];
            #pragma unroll
            for (int j = 0; j < 8; ++j) o[j] = fmaxf(acc[i][j] + bb[j], 0.f);
            uint4 pk;
            pk.x = (unsigned int)f2bf(o[0]) | ((unsigned int)f2bf(o[1]) << 16);
            pk.y = (unsigned int)f2bf(o[2]) | ((unsigned int)f2bf(o[3]) << 16);
            pk.z = (unsigned int)f2bf(o[4]) | ((unsigned int)f2bf(o[5]) << 16);
            pk.w = (unsigned int)f2bf(o[6]) | ((unsigned int)f2bf(o[7]) << 16);
            *(uint4*)(hid + (size_t)node*HC + tn*8) = pk;
        }
    }
}

// ----------------- MFMA GEMM -----------------
// ATT=false: C(bf16) = A@W + bias.  ATT=true: C8(fp8 e4m3) = A@W, + fused att dots.
template<bool ATT>
__global__ __launch_bounds__(256) void gemm_mfma_kernel(
        const unsigned short* __restrict__ A, const unsigned short* __restrict__ Wt,
        const float* __restrict__ bias,
        const float* __restrict__ att_s, const float* __restrict__ att_d,
        unsigned short* __restrict__ Cb, unsigned char* __restrict__ C8,
        float* __restrict__ asrc, float* __restrict__ adst, int n)
{
    __shared__ float lds[4][16][132];
    int t = threadIdx.x;
    int w = t >> 6, l = t & 63;
    int lane15 = l & 15, lanehi = l >> 4;
    int m0 = blockIdx.x * 64 + w * 16;

    f32x4 acc[8];
    #pragma unroll
    for (int ct = 0; ct < 8; ++ct) acc[ct] = (f32x4){0.f, 0.f, 0.f, 0.f};

    int ar = m0 + lane15; if (ar > n - 1) ar = n - 1;
    const unsigned short* Arow = A + (size_t)ar * HC;

    #pragma unroll
    for (int kc = 0; kc < 4; ++kc){
        bf16x8 af = *reinterpret_cast<const bf16x8*>(Arow + kc * 32 + lanehi * 8);
        #pragma unroll
        for (int ct = 0; ct < 8; ++ct){
            bf16x8 bf = *reinterpret_cast<const bf16x8*>(
                Wt + (size_t)(ct * 16 + lane15) * HC + kc * 32 + lanehi * 8);
            acc[ct] = __builtin_amdgcn_mfma_f32_16x16x32_bf16(af, bf, acc[ct], 0, 0, 0);
        }
    }

    if (ATT){
        float ats[8], atd[8];
        #pragma unroll
        for (int ct = 0; ct < 8; ++ct){
            ats[ct] = att_s[ct * 16 + lane15];
            atd[ct] = att_d[ct * 16 + lane15];
        }
        #pragma unroll
        for (int r = 0; r < 4; ++r){
            float sa0 = 0.f, sd0 = 0.f, sa1 = 0.f, sd1 = 0.f;
            #pragma unroll
            for (int ct = 0; ct < 4; ++ct){
                sa0 = fmaf(acc[ct][r], ats[ct], sa0);
                sd0 = fmaf(acc[ct][r], atd[ct], sd0);
            }
            #pragma unroll
            for (int ct = 4; ct < 8; ++ct){
                sa1 = fmaf(acc[ct][r], ats[ct], sa1);
                sd1 = fmaf(acc[ct][r], atd[ct], sd1);
            }
            #pragma unroll
            for (int o = 1; o < 16; o <<= 1){
                sa0 += __shfl_xor(sa0, o); sd0 += __shfl_xor(sd0, o);
                sa1 += __shfl_xor(sa1, o); sd1 += __shfl_xor(sd1, o);
            }
            int node = m0 + lanehi * 4 + r;
            if (lane15 == 0 && node < n){
                asrc[(size_t)node * 2]     = sa0;
                adst[(size_t)node * 2]     = sd0;
                asrc[(size_t)node * 2 + 1] = sa1;
                adst[(size_t)node * 2 + 1] = sd1;
            }
        }
    }

    float bb[8];
    #pragma unroll
    for (int ct = 0; ct < 8; ++ct) bb[ct] = ATT ? 0.f : bias[ct * 16 + lane15];
    #pragma unroll
    for (int ct = 0; ct < 8; ++ct)
        #pragma unroll
        for (int r = 0; r < 4; ++r)
            lds[w][lanehi * 4 + r][ct * 16 + lane15] = acc[ct][r] + bb[ct];
    __syncthreads();

    int row = lane15, cb = lanehi;
    int node = m0 + row;
    if (node < n){
        if (!ATT){
            #pragma unroll
            for (int q = 0; q < 4; ++q){
                float o[8];
                *(float4*)&o[0] = *(float4*)&lds[w][row][cb * 32 + q * 8];
                *(float4*)&o[4] = *(float4*)&lds[w][row][cb * 32 + q * 8 + 4];
                uint4 pk;
                pk.x = (unsigned int)f2bf(o[0]) | ((unsigned int)f2bf(o[1]) << 16);
                pk.y = (unsigned int)f2bf(o[2]) | ((unsigned int)f2bf(o[3]) << 16);
                pk.z = (unsigned int)f2bf(o[4]) | ((unsigned int)f2bf(o[5]) << 16);
                pk.w = (unsigned int)f2bf(o[6]) | ((unsigned int)f2bf(o[7]) << 16);
                *(uint4*)(Cb + (size_t)node * HC + cb * 32 + q * 8) = pk;
            }
        } else {
            unsigned int words[8];
            #pragma unroll
            for (int gq = 0; gq < 8; ++gq){
                float4 v = *(float4*)&lds[w][row][cb * 32 + gq * 4];
                unsigned int r = __builtin_amdgcn_cvt_pk_fp8_f32(v.x, v.y, 0, 0);
                r = __builtin_amdgcn_cvt_pk_fp8_f32(v.z, v.w, r, 1);
                words[gq] = r;
            }
            *(uint4*)(C8 + (size_t)node * HC + cb * 32)      = make_uint4(words[0], words[1], words[2], words[3]);
            *(uint4*)(C8 + (size_t)node * HC + cb * 32 + 16) = make_uint4(words[4], words[5], words[6], words[7]);
        }
    }
}

// ----------------- aggregation: 4 nodes/block, 4 edges/wave-iteration -----------------
// quarter-wave qw = t>>4 owns edge j+qw; lane covers 8 fp8 channels (uint2, 16 lanes = 128B row).
__global__ __launch_bounds__(256) void aggregate_kernel(
        const unsigned char* __restrict__ h8, const float* __restrict__ asrc,
        const float* __restrict__ adst,
        const int* __restrict__ rowptr, const int* __restrict__ colsrc,
        const float* __restrict__ bias, unsigned short* __restrict__ hout, int n)
{
    int i = blockIdx.x * 4 + (threadIdx.x >> 6);
    if (i >= n) return;
    int t = threadIdx.x & 63;
    int qw = t >> 4;              // quarter-wave: which of 4 edges this group processes
    int lc = t & 15;              // channels lc*8 .. lc*8+7
    int head = lc >> 3;           // lc*8 < 64 -> head0 else head1
    float2 adv = *(const float2*)(adst + (size_t)i * 2);
    float2 asv = *(const float2*)(asrc + (size_t)i * 2);
    // self loop: counted by quarter-wave 0 only
    float exs = __expf(lrelu((head ? asv.y : asv.x) + (head ? adv.y : adv.x)));
    float w0 = (qw == 0) ? exs : 0.f;
    uint2 hv = *(const uint2*)(h8 + (size_t)i * HC + lc * 8);
    float a0 = w0 * __builtin_amdgcn_cvt_f32_fp8(hv.x, 0);
    float a1 = w0 * __builtin_amdgcn_cvt_f32_fp8(hv.x, 1);
    float a2 = w0 * __builtin_amdgcn_cvt_f32_fp8(hv.x, 2);
    float a3 = w0 * __builtin_amdgcn_cvt_f32_fp8(hv.x, 3);
    float a4 = w0 * __builtin_amdgcn_cvt_f32_fp8(hv.y, 0);
    float a5 = w0 * __builtin_amdgcn_cvt_f32_fp8(hv.y, 1);
    float a6 = w0 * __builtin_amdgcn_cvt_f32_fp8(hv.y, 2);
    float a7 = w0 * __builtin_amdgcn_cvt_f32_fp8(hv.y, 3);
    float D = w0;

    int e  = rowptr[i];
    int e1 = rowptr[i + 1];
    while (e < e1){
        int m = e1 - e; if (m > 64) m = 64;
        int sl = 0; float ex0 = 0.f, ex1 = 0.f;
        if (t < m){
            sl = colsrc[e + t];                       // coalesced
            float2 as = *(const float2*)(asrc + (size_t)sl * 2);
            ex0 = __expf(lrelu(as.x + adv.x));
            ex1 = __expf(lrelu(as.y + adv.y));
        }
        int j = 0;
        for (; j + 8 <= m; j += 8){                   // 2 quads -> 2 gathers in flight/quarter-wave
            int s[2]; float c[2];
            #pragma unroll
            for (int u = 0; u < 2; ++u){
                int src = j + 4 * u + qw;
                s[u] = __shfl(sl, src);
                float c0 = __shfl(ex0, src);
                float c1 = __shfl(ex1, src);
                c[u] = head ? c1 : c0;
            }
            uint2 v[2];
            #pragma unroll
            for (int u = 0; u < 2; ++u)
                v[u] = *(const uint2*)(h8 + (size_t)s[u] * HC + lc * 8);
            #pragma unroll
            for (int u = 0; u < 2; ++u){
                a0 = fmaf(c[u], __builtin_amdgcn_cvt_f32_fp8(v[u].x, 0), a0);
                a1 = fmaf(c[u], __builtin_amdgcn_cvt_f32_fp8(v[u].x, 1), a1);
                a2 = fmaf(c[u], __builtin_amdgcn_cvt_f32_fp8(v[u].x, 2), a2);
                a3 = fmaf(c[u], __builtin_amdgcn_cvt_f32_fp8(v[u].x, 3), a3);
                a4 = fmaf(c[u], __builtin_amdgcn_cvt_f32_fp8(v[u].y, 0), a4);
                a5 = fmaf(c[u], __builtin_amdgcn_cvt_f32_fp8(v[u].y, 1), a5);
                a6 = fmaf(c[u], __builtin_amdgcn_cvt_f32_fp8(v[u].y, 2), a6);
                a7 = fmaf(c[u], __builtin_amdgcn_cvt_f32_fp8(v[u].y, 3), a7);
                D += c[u];
            }
        }
        for (; j + 4 <= m; j += 4){
            int src = j + qw;
            int   s  = __shfl(sl, src);
            float c0 = __shfl(ex0, src);
            float c1 = __shfl(ex1, src);
            float c = head ? c1 : c0;
            uint2 v = *(const uint2*)(h8 + (size_t)s * HC + lc * 8);
            a0 = fmaf(c, __builtin_amdgcn_cvt_f32_fp8(v.x, 0), a0);
            a1 = fmaf(c, __builtin_amdgcn_cvt_f32_fp8(v.x, 1), a1);
            a2 = fmaf(c, __builtin_amdgcn_cvt_f32_fp8(v.x, 2), a2);
            a3 = fmaf(c, __builtin_amdgcn_cvt_f32_fp8(v.x, 3), a3);
            a4 = fmaf(c, __builtin_amdgcn_cvt_f32_fp8(v.y, 0), a4);
            a5 = fmaf(c, __builtin_amdgcn_cvt_f32_fp8(v.y, 1), a5);
            a6 = fmaf(c, __builtin_amdgcn_cvt_f32_fp8(v.y, 2), a6);
            a7 = fmaf(c, __builtin_amdgcn_cvt_f32_fp8(v.y, 3), a7);
            D += c;
        }
        if (j < m){                                   // tail 1..3: quarter-waves < rem
            int rem = m - j;
            int src = j + qw;
            int   s  = __shfl(sl, src);
            float c0 = __shfl(ex0, src);
            float c1 = __shfl(ex1, src);
            float c = head ? c1 : c0;
            if (qw < rem){
                uint2 v = *(const uint2*)(h8 + (size_t)s * HC + lc * 8);
                a0 = fmaf(c, __builtin_amdgcn_cvt_f32_fp8(v.x, 0), a0);
                a1 = fmaf(c, __builtin_amdgcn_cvt_f32_fp8(v.x, 1), a1);
                a2 = fmaf(c, __builtin_amdgcn_cvt_f32_fp8(v.x, 2), a2);
                a3 = fmaf(c, __builtin_amdgcn_cvt_f32_fp8(v.x, 3), a3);
                a4 = fmaf(c, __builtin_amdgcn_cvt_f32_fp8(v.y, 0), a4);
                a5 = fmaf(c, __builtin_amdgcn_cvt_f32_fp8(v.y, 1), a5);
                a6 = fmaf(c, __builtin_amdgcn_cvt_f32_fp8(v.y, 2), a6);
                a7 = fmaf(c, __builtin_amdgcn_cvt_f32_fp8(v.y, 3), a7);
                D += c;
            }
        }
        e += m;
    }
    // combine the four quarter-waves (lanes t, t^16, t^32, t^48 share lc)
    a0 += __shfl_xor(a0, 16); a0 += __shfl_xor(a0, 32);
    a1 += __shfl_xor(a1, 16); a1 += __shfl_xor(a1, 32);
    a2 += __shfl_xor(a2, 16); a2 += __shfl_xor(a2, 32);
    a3 += __shfl_xor(a3, 16); a3 += __shfl_xor(a3, 32);
    a4 += __shfl_xor(a4, 16); a4 += __shfl_xor(a4, 32);
    a5 += __shfl_xor(a5, 16); a5 += __shfl_xor(a5, 32);
    a6 += __shfl_xor(a6, 16); a6 += __shfl_xor(a6, 32);
    a7 += __shfl_xor(a7, 16); a7 += __shfl_xor(a7, 32);
    D  += __shfl_xor(D, 16);  D  += __shfl_xor(D, 32);
    if (qw == 0){
        float rD = 1.0f / D;
        float4 b0 = *(const float4*)(bias + lc * 8);
        float4 b1v = *(const float4*)(bias + lc * 8 + 4);
        float o0 = fmaxf(a0 * rD + b0.x, 0.f);
        float o1 = fmaxf(a1 * rD + b0.y, 0.f);
        float o2 = fmaxf(a2 * rD + b0.z, 0.f);
        float o3 = fmaxf(a3 * rD + b0.w, 0.f);
        float o4 = fmaxf(a4 * rD + b1v.x, 0.f);
        float o5 = fmaxf(a5 * rD + b1v.y, 0.f);
        float o6 = fmaxf(a6 * rD + b1v.z, 0.f);
        float o7 = fmaxf(a7 * rD + b1v.w, 0.f);
        uint4 pk;
        pk.x = (unsigned int)f2bf(o0) | ((unsigned int)f2bf(o1) << 16);
        pk.y = (unsigned int)f2bf(o2) | ((unsigned int)f2bf(o3) << 16);
        pk.z = (unsigned int)f2bf(o4) | ((unsigned int)f2bf(o5) << 16);
        pk.w = (unsigned int)f2bf(o6) | ((unsigned int)f2bf(o7) << 16);
        *(uint4*)(hout + (size_t)i * HC + lc * 8) = pk;
    }
}

// ----------------- graph mean: two-stage, bf16 input -----------------
__global__ __launch_bounds__(256) void mean_part_kernel(
        const unsigned short* __restrict__ h, float* __restrict__ partial, int n)
{
    int t = threadIdx.x;
    int cq = t & 31;
    int rl = t >> 5;
    float4 acc = make_float4(0.f, 0.f, 0.f, 0.f);
    for (int i = blockIdx.x * 8 + rl; i < n; i += gridDim.x * 8){
        uint2 v = *(const uint2*)(h + (size_t)i * HC + cq * 4);
        acc.x += bf_lo(v.x); acc.y += bf_hi(v.x);
        acc.z += bf_lo(v.y); acc.w += bf_hi(v.y);
    }
    __shared__ float4 red[256];
    red[t] = acc;
    __syncthreads();
    if (t < 128){
        float4 o = red[t + 128];
        red[t].x += o.x; red[t].y += o.y; red[t].z += o.z; red[t].w += o.w;
    }
    __syncthreads();
    if (t < 64){
        float4 o = red[t + 64];
        red[t].x += o.x; red[t].y += o.y; red[t].z += o.z; red[t].w += o.w;
    }
    __syncthreads();
    if (t < 32){
        float4 a = red[t], b = red[t + 32];
        float4 s = make_float4(a.x + b.x, a.y + b.y, a.z + b.z, a.w + b.w);
        *(float4*)(partial + (size_t)blockIdx.x * HC + t * 4) = s;
    }
}

__global__ __launch_bounds__(256) void mean_fin_kernel(
        const float* __restrict__ partial, float* __restrict__ g, int nb)
{
    int t = threadIdx.x;
    int cq = t & 31, b0 = t >> 5;
    float4 acc = make_float4(0.f, 0.f, 0.f, 0.f);
    for (int b = b0; b < nb; b += 8){
        float4 v = *(const float4*)(partial + (size_t)b * HC + cq * 4);
        acc.x += v.x; acc.y += v.y; acc.z += v.z; acc.w += v.w;
    }
    __shared__ float4 red[256];
    red[t] = acc;
    __syncthreads();
    if (t < 128){
        float4 o = red[t + 128];
        red[t].x += o.x; red[t].y += o.y; red[t].z += o.z; red[t].w += o.w;
    }
    __syncthreads();
    if (t < 64){
        float4 o = red[t + 64];
        red[t].x += o.x; red[t].y += o.y; red[t].z += o.z; red[t].w += o.w;
    }
    __syncthreads();
    if (t < 32){
        float4 a = red[t], b = red[t + 32];
        float4 s = make_float4(a.x + b.x, a.y + b.y, a.z + b.z, a.w + b.w);
        *(float4*)(g + t * 4) = s;
    }
}

// ----------------- vuln head, MFMA -----------------
__global__ __launch_bounds__(256) void vuln_mfma_kernel(
        const unsigned short* __restrict__ h, const unsigned short* __restrict__ Wtv,
        const float* __restrict__ bv1, const float* __restrict__ wv2,
        const float* __restrict__ bv2, float* __restrict__ out, int n)
{
    int t = threadIdx.x;
    int w = t >> 6, l = t & 63;
    int lane15 = l & 15, lanehi = l >> 4;
    int m0 = blockIdx.x * 64 + w * 16;

    f32x4 acc[4];
    #pragma unroll
    for (int ct = 0; ct < 4; ++ct) acc[ct] = (f32x4){0.f, 0.f, 0.f, 0.f};

    int ar = m0 + lane15; if (ar > n - 1) ar = n - 1;
    const unsigned short* Arow = h + (size_t)ar * HC;

    #pragma unroll
    for (int kc = 0; kc < 4; ++kc){
        bf16x8 af = *reinterpret_cast<const bf16x8*>(Arow + kc * 32 + lanehi * 8);
        #pragma unroll
        for (int ct = 0; ct < 4; ++ct){
            bf16x8 bf = *reinterpret_cast<const bf16x8*>(
                Wtv + (size_t)(ct * 16 + lane15) * HC + kc * 32 + lanehi * 8);
            acc[ct] = __builtin_amdgcn_mfma_f32_16x16x32_bf16(af, bf, acc[ct], 0, 0, 0);
        }
    }

    float bb[4], wv[4];
    #pragma unroll
    for (int ct = 0; ct < 4; ++ct){
        bb[ct] = bv1[ct * 16 + lane15];
        wv[ct] = wv2[ct * 16 + lane15];
    }
    float bv2v = bv2[0];
    #pragma unroll
    for (int r = 0; r < 4; ++r){
        float s = 0.f;
        #pragma unroll
        for (int ct = 0; ct < 4; ++ct)
            s = fmaf(fmaxf(acc[ct][r] + bb[ct], 0.f), wv[ct], s);
        #pragma unroll
        for (int o = 1; o < 16; o <<= 1) s += __shfl_xor(s, o);
        int node = m0 + lanehi * 4 + r;
        if (lane15 == 0 && node < n)
            out[1 + node] = 1.0f / (1.0f + __expf(-(s + bv2v)));
    }
}

// ----------------- path head (1 block) -----------------
__global__ __launch_bounds__(128) void path_kernel(
        const unsigned short* __restrict__ h, const float* __restrict__ g,
        const float* __restrict__ wp1, const float* __restrict__ bp1,
        const float* __restrict__ wp2, const float* __restrict__ bp2,
        const float* __restrict__ wp3, const float* __restrict__ bp3,
        float* __restrict__ out, int n)
{
    __shared__ float pc[256];
    __shared__ float p1[HC];
    __shared__ float p2[64];
    int t = threadIdx.x;              // 128
    pc[t]       = bf1(h[t]);          // h[0,:]
    pc[128 + t] = g[t] * (1.0f / (float)n);
    __syncthreads();
    float a = bp1[t];
    for (int k = 0; k < 256; ++k) a = fmaf(pc[k], wp1[k * HC + t], a);
    p1[t] = fmaxf(a, 0.f);
    __syncthreads();
    if (t < 64){
        float a2 = bp2[t];
        for (int k = 0; k < HC; ++k) a2 = fmaf(p1[k], wp2[k * 64 + t], a2);
        p2[t] = fmaxf(a2, 0.f);
    }
    __syncthreads();
    if (t == 0){
        float a3 = bp3[0];
        for (int k = 0; k < 64; ++k) a3 = fmaf(p2[k], wp3[k], a3);
        out[0] = 1.0f / (1.0f + __expf(-a3));
        out[1 + n] = 0.f;             // esc = 0
    }
}

extern "C" void kernel_launch(void* const* d_in, const int* in_sizes, int n_in,
                              void* d_out, int out_size, void* d_ws, size_t ws_size,
                              hipStream_t stream)
{
    const float* x    = (const float*)d_in[0];
    const int*   ei   = (const int*)d_in[1];
    const float* w_n1 = (const float*)d_in[3];
    const float* b_n1 = (const float*)d_in[4];
    const float* w_n2 = (const float*)d_in[5];
    const float* b_n2 = (const float*)d_in[6];
    const float* conv_w = (const float*)d_in[9];
    const float* att_s  = (const float*)d_in[10];
    const float* att_d  = (const float*)d_in[11];
    const float* conv_b = (const float*)d_in[12];
    const float* wp1 = (const float*)d_in[13];
    const float* bp1 = (const float*)d_in[14];
    const float* wp2 = (const float*)d_in[15];
    const float* bp2 = (const float*)d_in[16];
    const float* wp3 = (const float*)d_in[17];
    const float* bp3 = (const float*)d_in[18];
    const float* wv1 = (const float*)d_in[19];
    const float* bv1 = (const float*)d_in[20];
    const float* wv2 = (const float*)d_in[21];
    const float* bv2 = (const float*)d_in[22];

    const int N = in_sizes[0] / 32;
    const int E = in_sizes[1] / 2;
    float* out = (float*)d_out;

    char* ws = (char*)d_ws;
    size_t off = 0;
    auto take = [&](size_t bytes) -> char* {
        char* p = ws + off;
        off += (bytes + 255) & ~(size_t)255;
        return p;
    };
    unsigned short* hA = (unsigned short*)take((size_t)N * HC * 2);  // bf16 node features
    unsigned short* hB = (unsigned short*)take((size_t)N * HC * 2);  // bf16 enc hidden
    unsigned char*  h8 = (unsigned char*)take((size_t)N * HC);      // fp8 h' for gathers
    float* asrc  = (float*)take((size_t)N * 2 * 4);
    float* adst  = (float*)take((size_t)N * 2 * 4);
    int*   rowptr= (int*)take((size_t)(N + 1) * 4);
    int*   cnt   = (int*)take((size_t)N * 4);
    int*   rank  = (int*)take((size_t)E * 4);
    int*   colsrc= (int*)take((size_t)E * 4);
    float* g     = (float*)take(HC * 4);
    unsigned short* Wt0 = (unsigned short*)take(16384 * 2);             // w_n2^T bf16
    unsigned short* Wt1 = (unsigned short*)take((size_t)3 * 16384 * 2); // conv_w^T bf16
    unsigned short* Wtv = (unsigned short*)take(8192 * 2);              // wv1^T bf16 (64x128)
    const int MB = 64;
    float* mpart = (float*)take((size_t)MB * HC * 4);
    int nb = (N + 1023) / 1024;
    int*   bsum  = (int*)take((size_t)((nb + 63) & ~63) * 4);
    int*   boff  = (int*)take((size_t)((nb + 63) & ~63) * 4);

    // --- CSR build (dst-sorted; reused across the 3 layers) ---
    hipMemsetAsync(cnt, 0, (size_t)N * 4, stream);
    count_kernel<<<(E + 255) / 256, 256, 0, stream>>>(ei, cnt, rank, E);
    scan_part_kernel<<<nb, 256, 0, stream>>>(cnt, bsum, N);
    scan_top_kernel<<<1, 64, 0, stream>>>(bsum, boff, rowptr, nb, N);
    scan_fin_kernel<<<nb, 256, 0, stream>>>(cnt, boff, rowptr, N);
    scatter_kernel<<<(E + 2047) / 2048, 256, 0, stream>>>(ei, rowptr, rank, colsrc, E);

    // --- weights -> transposed bf16 for MFMA B fragments (one dispatch) ---
    wtrans_all_kernel<<<36, 256, 0, stream>>>(w_n2, conv_w, wv1, Wt0, Wt1, Wtv);

    int nblk64 = (N + 63) / 64;
    // node encoder: hid (hB bf16) = relu(x@w1+b1); hA = hid@w2 + b2 (bf16, MFMA)
    enc1_kernel<<<nblk64, 256, 0, stream>>>(x, w_n1, b_n1, hB, N);
    gemm_mfma_kernel<false><<<nblk64, 256, 0, stream>>>(
        hB, Wt0, b_n2, nullptr, nullptr, hA, nullptr, nullptr, nullptr, N);

    for (int l = 0; l < 3; ++l){
        gemm_mfma_kernel<true><<<nblk64, 256, 0, stream>>>(
            hA, Wt1 + (size_t)l * 16384, nullptr,
            att_s + (size_t)l * HC, att_d + (size_t)l * HC,
            nullptr, h8, asrc, adst, N);
        aggregate_kernel<<<(N + 3) / 4, 256, 0, stream>>>(
            h8, asrc, adst, rowptr, colsrc, conv_b + (size_t)l * HC, hA, N);
    }

    mean_part_kernel<<<MB, 256, 0, stream>>>(hA, mpart, N);
    mean_fin_kernel<<<1, 256, 0, stream>>>(mpart, g, MB);
    vuln_mfma_kernel<<<nblk64, 256, 0, stream>>>(hA, Wtv, bv1, wv2, bv2, out, N);
    path_kernel<<<1, 128, 0, stream>>>(hA, g, wp1, bp1, wp2, bp2, wp3, bp3, out, N);
}

// Round 16
// 307.805 us; speedup vs baseline: 1.0044x; 1.0044x over previous
//
#include <hip/hip_runtime.h>
#include <math.h>

#define HC 128
#define NSLOPE 0.2f

using bf16x8 = __attribute__((ext_vector_type(8))) short;
using f32x4  = __attribute__((ext_vector_type(4))) float;

__device__ __forceinline__ float lrelu(float v){ return v > 0.f ? v : NSLOPE * v; }

// bf16 round-to-nearest-even pack / unpack
__device__ __forceinline__ unsigned short f2bf(float f){
    unsigned int b = __float_as_uint(f);
    b += 0x7FFFu + ((b >> 16) & 1u);
    return (unsigned short)(b >> 16);
}
__device__ __forceinline__ float bf_lo(unsigned int v){ return __uint_as_float(v << 16); }
__device__ __forceinline__ float bf_hi(unsigned int v){ return __uint_as_float(v & 0xFFFF0000u); }
__device__ __forceinline__ float bf1(unsigned short v){ return __uint_as_float((unsigned int)v << 16); }

// ----------------- CSR build (dst-sorted) -----------------
// count + per-edge rank, ILP=4 (4 independent atomic chains per thread)
__global__ __launch_bounds__(256) void count_kernel(
        const int* __restrict__ ei, int* __restrict__ cnt,
        int* __restrict__ rank, int E)
{
    int b = blockIdx.x * 1024 + threadIdx.x;
    int e[4]; bool v[4]; int d[4];
    #pragma unroll
    for (int i = 0; i < 4; ++i){ e[i] = b + i * 256; v[i] = e[i] < E; }
    #pragma unroll
    for (int i = 0; i < 4; ++i) if (v[i]) d[i] = ei[E + e[i]];
    int r[4];
    #pragma unroll
    for (int i = 0; i < 4; ++i) if (v[i]) r[i] = atomicAdd(&cnt[d[i]], 1);
    #pragma unroll
    for (int i = 0; i < 4; ++i) if (v[i]) rank[e[i]] = r[i];
}

__global__ __launch_bounds__(256) void scan_part_kernel(
        const int* __restrict__ deg, int* __restrict__ bsum, int n)
{
    int t = threadIdx.x, lane = t & 63, wid = t >> 6;
    int base = blockIdx.x * 1024 + t * 4;
    int s = 0;
    #pragma unroll
    for (int j = 0; j < 4; ++j){ int i = base + j; if (i < n) s += deg[i]; }
    #pragma unroll
    for (int o = 1; o < 64; o <<= 1) s += __shfl_xor(s, o);
    __shared__ int red[4];
    if (lane == 0) red[wid] = s;
    __syncthreads();
    if (t == 0) bsum[blockIdx.x] = red[0] + red[1] + red[2] + red[3];
}

__global__ __launch_bounds__(64) void scan_top_kernel(
        const int* __restrict__ bsum, int* __restrict__ boff, int* __restrict__ rowptr,
        int nb, int n)
{
    int t = threadIdx.x;
    int v = (t < nb) ? bsum[t] : 0;
    int incl = v;
    #pragma unroll
    for (int o = 1; o < 64; o <<= 1){ int u = __shfl_up(incl, o); if (t >= o) incl += u; }
    if (t < nb) boff[t] = incl - v;
    if (t == 63) rowptr[n] = incl;
}

__global__ __launch_bounds__(256) void scan_fin_kernel(
        const int* __restrict__ deg, const int* __restrict__ boff,
        int* __restrict__ rowptr, int n)
{
    int t = threadIdx.x, lane = t & 63, wid = t >> 6;
    int base = blockIdx.x * 1024 + t * 4;
    int d[4]; int s = 0;
    #pragma unroll
    for (int j = 0; j < 4; ++j){ int i = base + j; d[j] = (i < n) ? deg[i] : 0; s += d[j]; }
    int incl = s;
    #pragma unroll
    for (int o = 1; o < 64; o <<= 1){ int u = __shfl_up(incl, o); if (lane >= o) incl += u; }
    __shared__ int wsum[4];
    if (lane == 63) wsum[wid] = incl;
    __syncthreads();
    int off = boff[blockIdx.x] + (incl - s);
    for (int w = 0; w < wid; ++w) off += wsum[w];
    #pragma unroll
    for (int j = 0; j < 4; ++j){
        int i = base + j;
        if (i < n) rowptr[i] = off;
        off += d[j];
    }
}

// stateless scatter, ILP=8
__global__ __launch_bounds__(256) void scatter_kernel(
        const int* __restrict__ ei, const int* __restrict__ rowptr,
        const int* __restrict__ rank, int* __restrict__ colsrc, int E)
{
    int b = blockIdx.x * 2048 + threadIdx.x;
    int e[8]; bool v[8]; int d[8], s[8], r[8];
    #pragma unroll
    for (int i = 0; i < 8; ++i){ e[i] = b + i * 256; v[i] = e[i] < E; }
    #pragma unroll
    for (int i = 0; i < 8; ++i) if (v[i]){ d[i] = ei[E + e[i]]; s[i] = ei[e[i]]; r[i] = rank[e[i]]; }
    #pragma unroll
    for (int i = 0; i < 8; ++i) if (v[i]) colsrc[rowptr[d[i]] + r[i]] = s[i];
}

// ----------------- all weight transposes -> bf16 Wt[c][K=128], one dispatch -----------------
__global__ __launch_bounds__(256) void wtrans_all_kernel(
        const float* __restrict__ w_n2, const float* __restrict__ conv_w,
        const float* __restrict__ wv1,
        unsigned short* __restrict__ Wt0, unsigned short* __restrict__ Wt1,
        unsigned short* __restrict__ Wtv)
{
    int idx = blockIdx.x * 256 + threadIdx.x;
    if (idx >= 9216) return;
    const float* Wm; unsigned short* Wo; int C; int rem;
    if (idx < 2048){ Wm = w_n2; Wo = Wt0; C = 128; rem = idx; }
    else if (idx < 8192){
        int m2 = (idx - 2048) >> 11; rem = (idx - 2048) & 2047;
        Wm = conv_w + (size_t)m2 * 16384; Wo = Wt1 + (size_t)m2 * 16384; C = 128;
    } else { rem = idx - 8192; Wm = wv1; Wo = Wtv; C = 64; }
    int c = rem >> 4, kg = rem & 15;
    unsigned int pk[4];
    #pragma unroll
    for (int j = 0; j < 4; ++j){
        float a = Wm[(size_t)(kg*8 + j*2    ) * C + c];
        float b = Wm[(size_t)(kg*8 + j*2 + 1) * C + c];
        pk[j] = (unsigned int)f2bf(a) | ((unsigned int)f2bf(b) << 16);
    }
    *(uint4*)(Wo + (size_t)c * 128 + kg * 8) = make_uint4(pk[0], pk[1], pk[2], pk[3]);
}

// ----------------- node encoder stage 1: hid(bf16) = relu(x@w1+b1), K=32 -----------------
__global__ __launch_bounds__(256) void enc1_kernel(
        const float* __restrict__ x, const float* __restrict__ w1, const float* __restrict__ b1,
        unsigned short* __restrict__ hid, int n)
{
    __shared__ float As[32][68];
    __shared__ float Bs[32][128];
    int t = threadIdx.x;
    int m0 = blockIdx.x * 64;
    int tm = t >> 4, tn = t & 15;

    #pragma unroll
    for (int i = 0; i < 2; ++i){
        int f = i * 256 + t;
        int row = f >> 3, kq = f & 7;
        int gr = m0 + row; if (gr > n - 1) gr = n - 1;
        float4 v = *(const float4*)(x + (size_t)gr * 32 + kq * 4);
        As[kq*4+0][row] = v.x; As[kq*4+1][row] = v.y; As[kq*4+2][row] = v.z; As[kq*4+3][row] = v.w;
    }
    #pragma unroll
    for (int i = 0; i < 4; ++i){
        int f = i * 256 + t;
        int kk = f >> 5, nq = f & 31;
        *(float4*)&Bs[kk][nq*4] = *(const float4*)(w1 + (size_t)kk * 128 + nq * 4);
    }
    __syncthreads();

    float acc[4][8];
    #pragma unroll
    for (int i = 0; i < 4; ++i)
        #pragma unroll
        for (int j = 0; j < 8; ++j) acc[i][j] = 0.f;

    #pragma unroll 4
    for (int k = 0; k < 32; ++k){
        float a[4], b[8];
        *(float4*)&a[0] = *(float4*)&As[k][tm*4];
        *(float4*)&b[0] = *(float4*)&Bs[k][tn*8];
        *(float4*)&b[4] = *(float4*)&Bs[k][tn*8+4];
        #pragma unroll
        for (int i = 0; i < 4; ++i)
            #pragma unroll
            for (int j = 0; j < 8; ++j) acc[i][j] = fmaf(a[i], b[j], acc[i][j]);
    }

    float bb[8];
    *(float4*)&bb[0] = *(const float4*)(b1 + tn*8);
    *(float4*)&bb[4] = *(const float4*)(b1 + tn*8 + 4);
    #pragma unroll
    for (int i = 0; i < 4; ++i){
        int node = m0 + tm*4 + i;
        if (node < n){
            float o[8];
            #pragma unroll
            for (int j = 0; j < 8; ++j) o[j] = fmaxf(acc[i][j] + bb[j], 0.f);
            uint4 pk;
            pk.x = (unsigned int)f2bf(o[0]) | ((unsigned int)f2bf(o[1]) << 16);
            pk.y = (unsigned int)f2bf(o[2]) | ((unsigned int)f2bf(o[3]) << 16);
            pk.z = (unsigned int)f2bf(o[4]) | ((unsigned int)f2bf(o[5]) << 16);
            pk.w = (unsigned int)f2bf(o[6]) | ((unsigned int)f2bf(o[7]) << 16);
            *(uint4*)(hid + (size_t)node*HC + tn*8) = pk;
        }
    }
}

// ----------------- MFMA GEMM -----------------
// ATT=false: C(bf16) = A@W + bias.  ATT=true: C8(fp8 e4m3) = A@W, + fused att dots.
template<bool ATT>
__global__ __launch_bounds__(256) void gemm_mfma_kernel(
        const unsigned short* __restrict__ A, const unsigned short* __restrict__ Wt,
        const float* __restrict__ bias,
        const float* __restrict__ att_s, const float* __restrict__ att_d,
        unsigned short* __restrict__ Cb, unsigned char* __restrict__ C8,
        float* __restrict__ asrc, float* __restrict__ adst, int n)
{
    __shared__ float lds[4][16][132];
    int t = threadIdx.x;
    int w = t >> 6, l = t & 63;
    int lane15 = l & 15, lanehi = l >> 4;
    int m0 = blockIdx.x * 64 + w * 16;

    f32x4 acc[8];
    #pragma unroll
    for (int ct = 0; ct < 8; ++ct) acc[ct] = (f32x4){0.f, 0.f, 0.f, 0.f};

    int ar = m0 + lane15; if (ar > n - 1) ar = n - 1;
    const unsigned short* Arow = A + (size_t)ar * HC;

    #pragma unroll
    for (int kc = 0; kc < 4; ++kc){
        bf16x8 af = *reinterpret_cast<const bf16x8*>(Arow + kc * 32 + lanehi * 8);
        #pragma unroll
        for (int ct = 0; ct < 8; ++ct){
            bf16x8 bf = *reinterpret_cast<const bf16x8*>(
                Wt + (size_t)(ct * 16 + lane15) * HC + kc * 32 + lanehi * 8);
            acc[ct] = __builtin_amdgcn_mfma_f32_16x16x32_bf16(af, bf, acc[ct], 0, 0, 0);
        }
    }

    if (ATT){
        float ats[8], atd[8];
        #pragma unroll
        for (int ct = 0; ct < 8; ++ct){
            ats[ct] = att_s[ct * 16 + lane15];
            atd[ct] = att_d[ct * 16 + lane15];
        }
        #pragma unroll
        for (int r = 0; r < 4; ++r){
            float sa0 = 0.f, sd0 = 0.f, sa1 = 0.f, sd1 = 0.f;
            #pragma unroll
            for (int ct = 0; ct < 4; ++ct){
                sa0 = fmaf(acc[ct][r], ats[ct], sa0);
                sd0 = fmaf(acc[ct][r], atd[ct], sd0);
            }
            #pragma unroll
            for (int ct = 4; ct < 8; ++ct){
                sa1 = fmaf(acc[ct][r], ats[ct], sa1);
                sd1 = fmaf(acc[ct][r], atd[ct], sd1);
            }
            #pragma unroll
            for (int o = 1; o < 16; o <<= 1){
                sa0 += __shfl_xor(sa0, o); sd0 += __shfl_xor(sd0, o);
                sa1 += __shfl_xor(sa1, o); sd1 += __shfl_xor(sd1, o);
            }
            int node = m0 + lanehi * 4 + r;
            if (lane15 == 0 && node < n){
                asrc[(size_t)node * 2]     = sa0;
                adst[(size_t)node * 2]     = sd0;
                asrc[(size_t)node * 2 + 1] = sa1;
                adst[(size_t)node * 2 + 1] = sd1;
            }
        }
    }

    float bb[8];
    #pragma unroll
    for (int ct = 0; ct < 8; ++ct) bb[ct] = ATT ? 0.f : bias[ct * 16 + lane15];
    #pragma unroll
    for (int ct = 0; ct < 8; ++ct)
        #pragma unroll
        for (int r = 0; r < 4; ++r)
            lds[w][lanehi * 4 + r][ct * 16 + lane15] = acc[ct][r] + bb[ct];
    __syncthreads();

    int row = lane15, cb = lanehi;
    int node = m0 + row;
    if (node < n){
        if (!ATT){
            #pragma unroll
            for (int q = 0; q < 4; ++q){
                float o[8];
                *(float4*)&o[0] = *(float4*)&lds[w][row][cb * 32 + q * 8];
                *(float4*)&o[4] = *(float4*)&lds[w][row][cb * 32 + q * 8 + 4];
                uint4 pk;
                pk.x = (unsigned int)f2bf(o[0]) | ((unsigned int)f2bf(o[1]) << 16);
                pk.y = (unsigned int)f2bf(o[2]) | ((unsigned int)f2bf(o[3]) << 16);
                pk.z = (unsigned int)f2bf(o[4]) | ((unsigned int)f2bf(o[5]) << 16);
                pk.w = (unsigned int)f2bf(o[6]) | ((unsigned int)f2bf(o[7]) << 16);
                *(uint4*)(Cb + (size_t)node * HC + cb * 32 + q * 8) = pk;
            }
        } else {
            unsigned int words[8];
            #pragma unroll
            for (int gq = 0; gq < 8; ++gq){
                float4 v = *(float4*)&lds[w][row][cb * 32 + gq * 4];
                unsigned int r = __builtin_amdgcn_cvt_pk_fp8_f32(v.x, v.y, 0, 0);
                r = __builtin_amdgcn_cvt_pk_fp8_f32(v.z, v.w, r, 1);
                words[gq] = r;
            }
            *(uint4*)(C8 + (size_t)node * HC + cb * 32)      = make_uint4(words[0], words[1], words[2], words[3]);
            *(uint4*)(C8 + (size_t)node * HC + cb * 32 + 16) = make_uint4(words[4], words[5], words[6], words[7]);
        }
    }
}

// ----------------- aggregation: 4 nodes/block, 2 edges/wave-iteration (round-14 best) -----------
// half-wave hw = t>>5 owns edge j+hw; lane covers 4 fp8 channels (uint load, 32 lanes = 128B row).
__global__ __launch_bounds__(256) void aggregate_kernel(
        const unsigned char* __restrict__ h8, const float* __restrict__ asrc,
        const float* __restrict__ adst,
        const int* __restrict__ rowptr, const int* __restrict__ colsrc,
        const float* __restrict__ bias, unsigned short* __restrict__ hout, int n)
{
    int i = blockIdx.x * 4 + (threadIdx.x >> 6);
    if (i >= n) return;
    int t = threadIdx.x & 63;
    int hw = t >> 5;              // which edge of the pair this half-wave processes
    int lc = t & 31;              // channels lc*4 .. lc*4+3
    int head = lc >> 4;           // lc*4 < 64 -> head0 else head1
    float2 adv = *(const float2*)(adst + (size_t)i * 2);
    float2 asv = *(const float2*)(asrc + (size_t)i * 2);
    // self loop: counted by half-wave 0 only
    float exs = __expf(lrelu((head ? asv.y : asv.x) + (head ? adv.y : adv.x)));
    float w0 = hw ? 0.f : exs;
    unsigned int hv = *(const unsigned int*)(h8 + (size_t)i * HC + lc * 4);
    float a0 = w0 * __builtin_amdgcn_cvt_f32_fp8(hv, 0);
    float a1 = w0 * __builtin_amdgcn_cvt_f32_fp8(hv, 1);
    float a2 = w0 * __builtin_amdgcn_cvt_f32_fp8(hv, 2);
    float a3 = w0 * __builtin_amdgcn_cvt_f32_fp8(hv, 3);
    float D = w0;

    int e  = rowptr[i];
    int e1 = rowptr[i + 1];
    while (e < e1){
        int m = e1 - e; if (m > 64) m = 64;
        int sl = 0; float ex0 = 0.f, ex1 = 0.f;
        if (t < m){
            sl = colsrc[e + t];                       // coalesced
            float2 as = *(const float2*)(asrc + (size_t)sl * 2);
            ex0 = __expf(lrelu(as.x + adv.x));
            ex1 = __expf(lrelu(as.y + adv.y));
        }
        int j = 0;
        for (; j + 8 <= m; j += 8){                   // 4 pairs -> 4 gathers in flight/half-wave
            int   s[4]; float c[4];
            #pragma unroll
            for (int u = 0; u < 4; ++u){
                int src = j + 2 * u + hw;
                s[u] = __shfl(sl, src);
                float c0 = __shfl(ex0, src);
                float c1 = __shfl(ex1, src);
                c[u] = head ? c1 : c0;
            }
            unsigned int v[4];
            #pragma unroll
            for (int u = 0; u < 4; ++u)
                v[u] = *(const unsigned int*)(h8 + (size_t)s[u] * HC + lc * 4);
            #pragma unroll
            for (int u = 0; u < 4; ++u){
                a0 = fmaf(c[u], __builtin_amdgcn_cvt_f32_fp8(v[u], 0), a0);
                a1 = fmaf(c[u], __builtin_amdgcn_cvt_f32_fp8(v[u], 1), a1);
                a2 = fmaf(c[u], __builtin_amdgcn_cvt_f32_fp8(v[u], 2), a2);
                a3 = fmaf(c[u], __builtin_amdgcn_cvt_f32_fp8(v[u], 3), a3);
                D += c[u];
            }
        }
        for (; j + 2 <= m; j += 2){
            int src = j + hw;
            int   s  = __shfl(sl, src);
            float c0 = __shfl(ex0, src);
            float c1 = __shfl(ex1, src);
            float c = head ? c1 : c0;
            unsigned int v = *(const unsigned int*)(h8 + (size_t)s * HC + lc * 4);
            a0 = fmaf(c, __builtin_amdgcn_cvt_f32_fp8(v, 0), a0);
            a1 = fmaf(c, __builtin_amdgcn_cvt_f32_fp8(v, 1), a1);
            a2 = fmaf(c, __builtin_amdgcn_cvt_f32_fp8(v, 2), a2);
            a3 = fmaf(c, __builtin_amdgcn_cvt_f32_fp8(v, 3), a3);
            D += c;
        }
        if (j < m){                                   // odd tail: half-wave 0 only
            int   s  = __shfl(sl, j);
            float c0 = __shfl(ex0, j);
            float c1 = __shfl(ex1, j);
            float c = head ? c1 : c0;
            if (hw == 0){
                unsigned int v = *(const unsigned int*)(h8 + (size_t)s * HC + lc * 4);
                a0 = fmaf(c, __builtin_amdgcn_cvt_f32_fp8(v, 0), a0);
                a1 = fmaf(c, __builtin_amdgcn_cvt_f32_fp8(v, 1), a1);
                a2 = fmaf(c, __builtin_amdgcn_cvt_f32_fp8(v, 2), a2);
                a3 = fmaf(c, __builtin_amdgcn_cvt_f32_fp8(v, 3), a3);
                D += c;
            }
        }
        e += m;
    }
    // combine the two half-waves
    a0 += __shfl_xor(a0, 32);
    a1 += __shfl_xor(a1, 32);
    a2 += __shfl_xor(a2, 32);
    a3 += __shfl_xor(a3, 32);
    D  += __shfl_xor(D, 32);
    if (hw == 0){
        float rD = 1.0f / D;
        float4 bb = *(const float4*)(bias + lc * 4);
        float o0 = fmaxf(a0 * rD + bb.x, 0.f);
        float o1 = fmaxf(a1 * rD + bb.y, 0.f);
        float o2 = fmaxf(a2 * rD + bb.z, 0.f);
        float o3 = fmaxf(a3 * rD + bb.w, 0.f);
        uint2 pk;
        pk.x = (unsigned int)f2bf(o0) | ((unsigned int)f2bf(o1) << 16);
        pk.y = (unsigned int)f2bf(o2) | ((unsigned int)f2bf(o3) << 16);
        *(uint2*)(hout + (size_t)i * HC + lc * 4) = pk;
    }
}

// ----------------- graph mean: two-stage, bf16 input -----------------
__global__ __launch_bounds__(256) void mean_part_kernel(
        const unsigned short* __restrict__ h, float* __restrict__ partial, int n)
{
    int t = threadIdx.x;
    int cq = t & 31;
    int rl = t >> 5;
    float4 acc = make_float4(0.f, 0.f, 0.f, 0.f);
    for (int i = blockIdx.x * 8 + rl; i < n; i += gridDim.x * 8){
        uint2 v = *(const uint2*)(h + (size_t)i * HC + cq * 4);
        acc.x += bf_lo(v.x); acc.y += bf_hi(v.x);
        acc.z += bf_lo(v.y); acc.w += bf_hi(v.y);
    }
    __shared__ float4 red[256];
    red[t] = acc;
    __syncthreads();
    if (t < 128){
        float4 o = red[t + 128];
        red[t].x += o.x; red[t].y += o.y; red[t].z += o.z; red[t].w += o.w;
    }
    __syncthreads();
    if (t < 64){
        float4 o = red[t + 64];
        red[t].x += o.x; red[t].y += o.y; red[t].z += o.z; red[t].w += o.w;
    }
    __syncthreads();
    if (t < 32){
        float4 a = red[t], b = red[t + 32];
        float4 s = make_float4(a.x + b.x, a.y + b.y, a.z + b.z, a.w + b.w);
        *(float4*)(partial + (size_t)blockIdx.x * HC + t * 4) = s;
    }
}

__global__ __launch_bounds__(256) void mean_fin_kernel(
        const float* __restrict__ partial, float* __restrict__ g, int nb)
{
    int t = threadIdx.x;
    int cq = t & 31, b0 = t >> 5;
    float4 acc = make_float4(0.f, 0.f, 0.f, 0.f);
    for (int b = b0; b < nb; b += 8){
        float4 v = *(const float4*)(partial + (size_t)b * HC + cq * 4);
        acc.x += v.x; acc.y += v.y; acc.z += v.z; acc.w += v.w;
    }
    __shared__ float4 red[256];
    red[t] = acc;
    __syncthreads();
    if (t < 128){
        float4 o = red[t + 128];
        red[t].x += o.x; red[t].y += o.y; red[t].z += o.z; red[t].w += o.w;
    }
    __syncthreads();
    if (t < 64){
        float4 o = red[t + 64];
        red[t].x += o.x; red[t].y += o.y; red[t].z += o.z; red[t].w += o.w;
    }
    __syncthreads();
    if (t < 32){
        float4 a = red[t], b = red[t + 32];
        float4 s = make_float4(a.x + b.x, a.y + b.y, a.z + b.z, a.w + b.w);
        *(float4*)(g + t * 4) = s;
    }
}

// ----------------- vuln head, MFMA -----------------
__global__ __launch_bounds__(256) void vuln_mfma_kernel(
        const unsigned short* __restrict__ h, const unsigned short* __restrict__ Wtv,
        const float* __restrict__ bv1, const float* __restrict__ wv2,
        const float* __restrict__ bv2, float* __restrict__ out, int n)
{
    int t = threadIdx.x;
    int w = t >> 6, l = t & 63;
    int lane15 = l & 15, lanehi = l >> 4;
    int m0 = blockIdx.x * 64 + w * 16;

    f32x4 acc[4];
    #pragma unroll
    for (int ct = 0; ct < 4; ++ct) acc[ct] = (f32x4){0.f, 0.f, 0.f, 0.f};

    int ar = m0 + lane15; if (ar > n - 1) ar = n - 1;
    const unsigned short* Arow = h + (size_t)ar * HC;

    #pragma unroll
    for (int kc = 0; kc < 4; ++kc){
        bf16x8 af = *reinterpret_cast<const bf16x8*>(Arow + kc * 32 + lanehi * 8);
        #pragma unroll
        for (int ct = 0; ct < 4; ++ct){
            bf16x8 bf = *reinterpret_cast<const bf16x8*>(
                Wtv + (size_t)(ct * 16 + lane15) * HC + kc * 32 + lanehi * 8);
            acc[ct] = __builtin_amdgcn_mfma_f32_16x16x32_bf16(af, bf, acc[ct], 0, 0, 0);
        }
    }

    float bb[4], wv[4];
    #pragma unroll
    for (int ct = 0; ct < 4; ++ct){
        bb[ct] = bv1[ct * 16 + lane15];
        wv[ct] = wv2[ct * 16 + lane15];
    }
    float bv2v = bv2[0];
    #pragma unroll
    for (int r = 0; r < 4; ++r){
        float s = 0.f;
        #pragma unroll
        for (int ct = 0; ct < 4; ++ct)
            s = fmaf(fmaxf(acc[ct][r] + bb[ct], 0.f), wv[ct], s);
        #pragma unroll
        for (int o = 1; o < 16; o <<= 1) s += __shfl_xor(s, o);
        int node = m0 + lanehi * 4 + r;
        if (lane15 == 0 && node < n)
            out[1 + node] = 1.0f / (1.0f + __expf(-(s + bv2v)));
    }
}

// ----------------- path head (1 block) -----------------
__global__ __launch_bounds__(128) void path_kernel(
        const unsigned short* __restrict__ h, const float* __restrict__ g,
        const float* __restrict__ wp1, const float* __restrict__ bp1,
        const float* __restrict__ wp2, const float* __restrict__ bp2,
        const float* __restrict__ wp3, const float* __restrict__ bp3,
        float* __restrict__ out, int n)
{
    __shared__ float pc[256];
    __shared__ float p1[HC];
    __shared__ float p2[64];
    int t = threadIdx.x;              // 128
    pc[t]       = bf1(h[t]);          // h[0,:]
    pc[128 + t] = g[t] * (1.0f / (float)n);
    __syncthreads();
    float a = bp1[t];
    for (int k = 0; k < 256; ++k) a = fmaf(pc[k], wp1[k * HC + t], a);
    p1[t] = fmaxf(a, 0.f);
    __syncthreads();
    if (t < 64){
        float a2 = bp2[t];
        for (int k = 0; k < HC; ++k) a2 = fmaf(p1[k], wp2[k * 64 + t], a2);
        p2[t] = fmaxf(a2, 0.f);
    }
    __syncthreads();
    if (t == 0){
        float a3 = bp3[0];
        for (int k = 0; k < 64; ++k) a3 = fmaf(p2[k], wp3[k], a3);
        out[0] = 1.0f / (1.0f + __expf(-a3));
        out[1 + n] = 0.f;             // esc = 0
    }
}

extern "C" void kernel_launch(void* const* d_in, const int* in_sizes, int n_in,
                              void* d_out, int out_size, void* d_ws, size_t ws_size,
                              hipStream_t stream)
{
    const float* x    = (const float*)d_in[0];
    const int*   ei   = (const int*)d_in[1];
    const float* w_n1 = (const float*)d_in[3];
    const float* b_n1 = (const float*)d_in[4];
    const float* w_n2 = (const float*)d_in[5];
    const float* b_n2 = (const float*)d_in[6];
    const float* conv_w = (const float*)d_in[9];
    const float* att_s  = (const float*)d_in[10];
    const float* att_d  = (const float*)d_in[11];
    const float* conv_b = (const float*)d_in[12];
    const float* wp1 = (const float*)d_in[13];
    const float* bp1 = (const float*)d_in[14];
    const float* wp2 = (const float*)d_in[15];
    const float* bp2 = (const float*)d_in[16];
    const float* wp3 = (const float*)d_in[17];
    const float* bp3 = (const float*)d_in[18];
    const float* wv1 = (const float*)d_in[19];
    const float* bv1 = (const float*)d_in[20];
    const float* wv2 = (const float*)d_in[21];
    const float* bv2 = (const float*)d_in[22];

    const int N = in_sizes[0] / 32;
    const int E = in_sizes[1] / 2;
    float* out = (float*)d_out;

    char* ws = (char*)d_ws;
    size_t off = 0;
    auto take = [&](size_t bytes) -> char* {
        char* p = ws + off;
        off += (bytes + 255) & ~(size_t)255;
        return p;
    };
    unsigned short* hA = (unsigned short*)take((size_t)N * HC * 2);  // bf16 node features
    unsigned short* hB = (unsigned short*)take((size_t)N * HC * 2);  // bf16 enc hidden
    unsigned char*  h8 = (unsigned char*)take((size_t)N * HC);      // fp8 h' for gathers
    float* asrc  = (float*)take((size_t)N * 2 * 4);
    float* adst  = (float*)take((size_t)N * 2 * 4);
    int*   rowptr= (int*)take((size_t)(N + 1) * 4);
    int*   cnt   = (int*)take((size_t)N * 4);
    int*   rank  = (int*)take((size_t)E * 4);
    int*   colsrc= (int*)take((size_t)E * 4);
    float* g     = (float*)take(HC * 4);
    unsigned short* Wt0 = (unsigned short*)take(16384 * 2);             // w_n2^T bf16
    unsigned short* Wt1 = (unsigned short*)take((size_t)3 * 16384 * 2); // conv_w^T bf16
    unsigned short* Wtv = (unsigned short*)take(8192 * 2);              // wv1^T bf16 (64x128)
    const int MB = 64;
    float* mpart = (float*)take((size_t)MB * HC * 4);
    int nb = (N + 1023) / 1024;
    int*   bsum  = (int*)take((size_t)((nb + 63) & ~63) * 4);
    int*   boff  = (int*)take((size_t)((nb + 63) & ~63) * 4);

    // --- CSR build (dst-sorted; reused across the 3 layers) ---
    hipMemsetAsync(cnt, 0, (size_t)N * 4, stream);
    count_kernel<<<(E + 1023) / 1024, 256, 0, stream>>>(ei, cnt, rank, E);
    scan_part_kernel<<<nb, 256, 0, stream>>>(cnt, bsum, N);
    scan_top_kernel<<<1, 64, 0, stream>>>(bsum, boff, rowptr, nb, N);
    scan_fin_kernel<<<nb, 256, 0, stream>>>(cnt, boff, rowptr, N);
    scatter_kernel<<<(E + 2047) / 2048, 256, 0, stream>>>(ei, rowptr, rank, colsrc, E);

    // --- weights -> transposed bf16 for MFMA B fragments (one dispatch) ---
    wtrans_all_kernel<<<36, 256, 0, stream>>>(w_n2, conv_w, wv1, Wt0, Wt1, Wtv);

    int nblk64 = (N + 63) / 64;
    // node encoder: hid (hB bf16) = relu(x@w1+b1); hA = hid@w2 + b2 (bf16, MFMA)
    enc1_kernel<<<nblk64, 256, 0, stream>>>(x, w_n1, b_n1, hB, N);
    gemm_mfma_kernel<false><<<nblk64, 256, 0, stream>>>(
        hB, Wt0, b_n2, nullptr, nullptr, hA, nullptr, nullptr, nullptr, N);

    for (int l = 0; l < 3; ++l){
        gemm_mfma_kernel<true><<<nblk64, 256, 0, stream>>>(
            hA, Wt1 + (size_t)l * 16384, nullptr,
            att_s + (size_t)l * HC, att_d + (size_t)l * HC,
            nullptr, h8, asrc, adst, N);
        aggregate_kernel<<<(N + 3) / 4, 256, 0, stream>>>(
            h8, asrc, adst, rowptr, colsrc, conv_b + (size_t)l * HC, hA, N);
    }

    mean_part_kernel<<<MB, 256, 0, stream>>>(hA, mpart, N);
    mean_fin_kernel<<<1, 256, 0, stream>>>(mpart, g, MB);
    vuln_mfma_kernel<<<nblk64, 256, 0, stream>>>(hA, Wtv, bv1, wv2, bv2, out, N);
    path_kernel<<<1, 128, 0, stream>>>(hA, g, wp1, bp1, wp2, bp2, wp3, bp3, out, N);
}